// Round 1
// baseline (345.369 us; speedup 1.0000x reference)
//
#include <hip/hip_runtime.h>

#define LDIM 128
#define NDIM 4096
#define EDIM 12
#define HDIM 32

// ---- LDS weight layout (float offsets) ----
#define W_INW   0       // [36][12]
#define W_INB   432     // [36]
#define W_OUTW  468     // [12][12]
#define W_OUTB  612     // [12]
#define W_W1    624     // [32][12]
#define W_B1    1008    // [32]
#define W_W2    1040    // [32][32]
#define W_B2    2064    // [32]
#define W_W3    2096    // [12][32]
#define W_B3    2480    // [12]
#define W_G1    2492
#define W_BE1   2504
#define W_G2    2516
#define W_BE2   2528
#define W_TOT   2540

#ifndef __has_builtin
#define __has_builtin(x) 0
#endif

__device__ __forceinline__ float ex2_(float v) {
#if __has_builtin(__builtin_amdgcn_exp2f)
    return __builtin_amdgcn_exp2f(v);
#else
    return exp2f(v);
#endif
}
__device__ __forceinline__ float rcp_(float v) {
#if __has_builtin(__builtin_amdgcn_rcpf)
    return __builtin_amdgcn_rcpf(v);
#else
    return 1.0f / v;
#endif
}
__device__ __forceinline__ float rsq_(float v) {
#if __has_builtin(__builtin_amdgcn_rsqf)
    return __builtin_amdgcn_rsqf(v);
#else
    return rsqrtf(v);
#endif
}
// tanh(v) = 1 - 2/(e^{2v}+1); exact at +-inf, ~1ulp error
__device__ __forceinline__ float tanh_(float v) {
    float t = ex2_(v * 2.8853900817779268f);   // e^{2v} = 2^{2v*log2(e)}
    return 1.0f - 2.0f * rcp_(t + 1.0f);
}

__device__ __forceinline__ float dot12(const float* __restrict__ w, const float* __restrict__ v) {
    const float4* w4 = reinterpret_cast<const float4*>(w);
    float4 a = w4[0], b = w4[1], c = w4[2];
    return a.x*v[0] + a.y*v[1] + a.z*v[2] + a.w*v[3]
         + b.x*v[4] + b.y*v[5] + b.z*v[6] + b.w*v[7]
         + c.x*v[8] + c.y*v[9] + c.z*v[10] + c.w*v[11];
}

__global__ __launch_bounds__(128, 4)
void encoder_fused(const float* __restrict__ x,
                   const float* __restrict__ inw, const float* __restrict__ inb,
                   const float* __restrict__ ow,  const float* __restrict__ ob,
                   const float* __restrict__ w1,  const float* __restrict__ b1,
                   const float* __restrict__ w2,  const float* __restrict__ b2,
                   const float* __restrict__ w3,  const float* __restrict__ b3,
                   const float* __restrict__ g1,  const float* __restrict__ be1,
                   const float* __restrict__ g2,  const float* __restrict__ be2,
                   float* __restrict__ out)
{
    const int n = blockIdx.x;   // batch element
    const int l = threadIdx.x;  // sequence row

    __shared__ float  sW[W_TOT];
    __shared__ float4 sK4[3][LDIM];   // chunk-major K: conflict-free b128 writes
    __shared__ float4 sV4[3][LDIM];
    __shared__ float  sMk[2];

    // ---- load this thread's x row: 3x dwordx4 ----
    const float* xrow = x + ((size_t)l * NDIM + n) * EDIM;
    float4 xa = *reinterpret_cast<const float4*>(xrow);
    float4 xb = *reinterpret_cast<const float4*>(xrow + 4);
    float4 xc = *reinterpret_cast<const float4*>(xrow + 8);
    float xr[EDIM] = {xa.x, xa.y, xa.z, xa.w, xb.x, xb.y, xb.z, xb.w, xc.x, xc.y, xc.z, xc.w};

    // ---- cooperative weight load into LDS ----
    for (int i = l; i < 432;  i += LDIM) sW[W_INW  + i] = inw[i];
    if (l < 36) sW[W_INB + l] = inb[l];
    for (int i = l; i < 144;  i += LDIM) sW[W_OUTW + i] = ow[i];
    for (int i = l; i < 384;  i += LDIM) sW[W_W1   + i] = w1[i];
    for (int i = l; i < 1024; i += LDIM) sW[W_W2   + i] = w2[i];
    for (int i = l; i < 384;  i += LDIM) sW[W_W3   + i] = w3[i];
    if (l < 32) { sW[W_B1 + l] = b1[l]; sW[W_B2 + l] = b2[l]; }
    if (l < 12) {
        sW[W_OUTB + l] = ob[l];  sW[W_B3  + l] = b3[l];
        sW[W_G1   + l] = g1[l];  sW[W_BE1 + l] = be1[l];
        sW[W_G2   + l] = g2[l];  sW[W_BE2 + l] = be2[l];
    }
    __syncthreads();

    // ---- QKV projection (q scaled by 1/sqrt(E)) ----
    const float SCALE = 0.2886751345948129f;  // 1/sqrt(12)
    float q[EDIM];
    float qq = 0.f;
    #pragma unroll
    for (int f = 0; f < EDIM; ++f) {
        float a = sW[W_INB + f] + dot12(&sW[W_INW + f * EDIM], xr);
        a *= SCALE;
        q[f] = a; qq += a * a;
    }
    float kv[EDIM];
    float kn = 0.f;
    #pragma unroll
    for (int f = 0; f < EDIM; ++f) {
        float a = sW[W_INB + 12 + f] + dot12(&sW[W_INW + (12 + f) * EDIM], xr);
        kv[f] = a; kn += a * a;
    }
    sK4[0][l] = make_float4(kv[0], kv[1], kv[2],  kv[3]);
    sK4[1][l] = make_float4(kv[4], kv[5], kv[6],  kv[7]);
    sK4[2][l] = make_float4(kv[8], kv[9], kv[10], kv[11]);
    #pragma unroll
    for (int f = 0; f < EDIM; ++f)
        kv[f] = sW[W_INB + 24 + f] + dot12(&sW[W_INW + (24 + f) * EDIM], xr);
    sV4[0][l] = make_float4(kv[0], kv[1], kv[2],  kv[3]);
    sV4[1][l] = make_float4(kv[4], kv[5], kv[6],  kv[7]);
    sV4[2][l] = make_float4(kv[8], kv[9], kv[10], kv[11]);

    // wave-level max of ||k||^2 -> block max (softmax shift bound)
    float mk = kn;
    #pragma unroll
    for (int off = 32; off > 0; off >>= 1) mk = fmaxf(mk, __shfl_xor(mk, off));
    if ((l & 63) == 0) sMk[l >> 6] = mk;
    __syncthreads();
    // Cauchy-Schwarz: s = (q*scale).k <= ||q*scale|| * max||k|| = M  (so s-M<=0)
    const float M = sqrtf(qq * fmaxf(sMk[0], sMk[1]));

    // ---- single-pass attention: p = exp(s - M), acc += p*V ----
    const float L2E = 1.4426950408889634f;
    float acc[EDIM] = {0,0,0,0,0,0,0,0,0,0,0,0};
    float lsum = 0.f;
    #pragma unroll 4
    for (int m = 0; m < LDIM; ++m) {
        float4 k0 = sK4[0][m], k1 = sK4[1][m], k2 = sK4[2][m];
        float s = q[0]*k0.x + q[1]*k0.y + q[2]*k0.z + q[3]*k0.w
                + q[4]*k1.x + q[5]*k1.y + q[6]*k1.z + q[7]*k1.w
                + q[8]*k2.x + q[9]*k2.y + q[10]*k2.z + q[11]*k2.w;
        float p = ex2_((s - M) * L2E);
        float4 v0 = sV4[0][m], v1 = sV4[1][m], v2 = sV4[2][m];
        lsum += p;
        acc[0] += p*v0.x; acc[1] += p*v0.y; acc[2]  += p*v0.z; acc[3]  += p*v0.w;
        acc[4] += p*v1.x; acc[5] += p*v1.y; acc[6]  += p*v1.z; acc[7]  += p*v1.w;
        acc[8] += p*v2.x; acc[9] += p*v2.y; acc[10] += p*v2.z; acc[11] += p*v2.w;
    }
    const float inv = rcp_(fmaxf(lsum, 1e-35f));
    float at[EDIM];
    #pragma unroll
    for (int e = 0; e < EDIM; ++e) at[e] = acc[e] * inv;

    // ---- out projection + residual + LN1 ----
    float r[EDIM];
    #pragma unroll
    for (int f = 0; f < EDIM; ++f)
        r[f] = xr[f] + sW[W_OUTB + f] + dot12(&sW[W_OUTW + f * EDIM], at);
    float mu = 0.f;
    #pragma unroll
    for (int e = 0; e < EDIM; ++e) mu += r[e];
    mu *= (1.0f / 12.0f);
    float var = 0.f;
    #pragma unroll
    for (int e = 0; e < EDIM; ++e) { float d = r[e] - mu; var += d * d; }
    var *= (1.0f / 12.0f);
    float rs = rsq_(var + 1e-5f);
    float y[EDIM];
    #pragma unroll
    for (int e = 0; e < EDIM; ++e)
        y[e] = (r[e] - mu) * rs * sW[W_G1 + e] + sW[W_BE1 + e];

    // ---- MLP: 12 -> 32 -> 32 -> 12, tanh each ----
    float h1v[HDIM];
    #pragma unroll
    for (int h = 0; h < HDIM; ++h)
        h1v[h] = tanh_(sW[W_B1 + h] + dot12(&sW[W_W1 + h * EDIM], y));
    float h2v[HDIM];
    #pragma unroll
    for (int g = 0; g < HDIM; ++g) {
        const float4* w4 = reinterpret_cast<const float4*>(&sW[W_W2 + g * HDIM]);
        float a = sW[W_B2 + g];
        #pragma unroll
        for (int c = 0; c < 8; ++c) {
            float4 w = w4[c];
            a += w.x*h1v[4*c] + w.y*h1v[4*c+1] + w.z*h1v[4*c+2] + w.w*h1v[4*c+3];
        }
        h2v[g] = tanh_(a);
    }
    float r2[EDIM];
    #pragma unroll
    for (int e = 0; e < EDIM; ++e) {
        const float4* w4 = reinterpret_cast<const float4*>(&sW[W_W3 + e * HDIM]);
        float a = sW[W_B3 + e];
        #pragma unroll
        for (int c = 0; c < 8; ++c) {
            float4 w = w4[c];
            a += w.x*h2v[4*c] + w.y*h2v[4*c+1] + w.z*h2v[4*c+2] + w.w*h2v[4*c+3];
        }
        r2[e] = y[e] + tanh_(a);
    }

    // ---- LN2 + store ----
    float mu2 = 0.f;
    #pragma unroll
    for (int e = 0; e < EDIM; ++e) mu2 += r2[e];
    mu2 *= (1.0f / 12.0f);
    float var2 = 0.f;
    #pragma unroll
    for (int e = 0; e < EDIM; ++e) { float d = r2[e] - mu2; var2 += d * d; }
    var2 *= (1.0f / 12.0f);
    float rs2 = rsq_(var2 + 1e-5f);
    float z[EDIM];
    #pragma unroll
    for (int e = 0; e < EDIM; ++e)
        z[e] = (r2[e] - mu2) * rs2 * sW[W_G2 + e] + sW[W_BE2 + e];

    float* orow = out + ((size_t)l * NDIM + n) * EDIM;
    *reinterpret_cast<float4*>(orow)     = make_float4(z[0], z[1], z[2],  z[3]);
    *reinterpret_cast<float4*>(orow + 4) = make_float4(z[4], z[5], z[6],  z[7]);
    *reinterpret_cast<float4*>(orow + 8) = make_float4(z[8], z[9], z[10], z[11]);
}

extern "C" void kernel_launch(void* const* d_in, const int* in_sizes, int n_in,
                              void* d_out, int out_size, void* d_ws, size_t ws_size,
                              hipStream_t stream) {
    const float* x   = (const float*)d_in[0];
    const float* inw = (const float*)d_in[1];
    const float* inb = (const float*)d_in[2];
    const float* ow  = (const float*)d_in[3];
    const float* ob  = (const float*)d_in[4];
    const float* w1  = (const float*)d_in[5];
    const float* b1  = (const float*)d_in[6];
    const float* w2  = (const float*)d_in[7];
    const float* b2  = (const float*)d_in[8];
    const float* w3  = (const float*)d_in[9];
    const float* b3  = (const float*)d_in[10];
    const float* g1  = (const float*)d_in[11];
    const float* be1 = (const float*)d_in[12];
    const float* g2  = (const float*)d_in[13];
    const float* be2 = (const float*)d_in[14];
    float* out = (float*)d_out;

    encoder_fused<<<dim3(NDIM), dim3(LDIM), 0, stream>>>(
        x, inw, inb, ow, ob, w1, b1, w2, b2, w3, b3, g1, be1, g2, be2, out);
}

// Round 2
// 278.110 us; speedup vs baseline: 1.2418x; 1.2418x over previous
//
#include <hip/hip_runtime.h>

#define NDIM 4096
#define LDIM 128
#define EDIM 12
#define HDIM 32
#define NB   4      // batch elements per block (one per wave)

#ifndef __has_builtin
#define __has_builtin(x) 0
#endif

__device__ __forceinline__ float ex2_(float v) {
#if __has_builtin(__builtin_amdgcn_exp2f)
    return __builtin_amdgcn_exp2f(v);
#else
    return exp2f(v);
#endif
}
__device__ __forceinline__ float rcp_(float v) {
#if __has_builtin(__builtin_amdgcn_rcpf)
    return __builtin_amdgcn_rcpf(v);
#else
    return 1.0f / v;
#endif
}
__device__ __forceinline__ float rsq_(float v) {
#if __has_builtin(__builtin_amdgcn_rsqf)
    return __builtin_amdgcn_rsqf(v);
#else
    return rsqrtf(v);
#endif
}
// tanh(v) = 1 - 2/(e^{2v}+1)
__device__ __forceinline__ float tanh_(float v) {
    float t = ex2_(v * 2.8853900817779268f);
    return 1.0f - 2.0f * rcp_(t + 1.0f);
}

// dot of 12-elem weight row (GLOBAL, uniform address -> s_load) with registers
__device__ __forceinline__ float dot12g(const float* __restrict__ w, const float* v) {
    const float4* w4 = reinterpret_cast<const float4*>(w);
    float4 a = w4[0], b = w4[1], c = w4[2];
    return a.x*v[0] + a.y*v[1] + a.z*v[2] + a.w*v[3]
         + b.x*v[4] + b.y*v[5] + b.z*v[6] + b.w*v[7]
         + c.x*v[8] + c.y*v[9] + c.z*v[10] + c.w*v[11];
}
__device__ __forceinline__ float dot32g(const float* __restrict__ w, const float* v) {
    const float4* w4 = reinterpret_cast<const float4*>(w);
    float acc = 0.f;
    #pragma unroll
    for (int c = 0; c < 8; ++c) {
        float4 t = w4[c];
        acc += t.x*v[4*c] + t.y*v[4*c+1] + t.z*v[4*c+2] + t.w*v[4*c+3];
    }
    return acc;
}

// round-to-nearest-even f32 -> bf16 pair packed into one uint
__device__ __forceinline__ unsigned int bfpair(float lo, float hi) {
    unsigned int a = __float_as_uint(lo), b = __float_as_uint(hi);
    a = (a + 0x7fffu + ((a >> 16) & 1u)) >> 16;
    b = (b + 0x7fffu + ((b >> 16) & 1u)) >> 16;
    return a | (b << 16);
}
__device__ __forceinline__ float bflo(unsigned int u) { return __uint_as_float(u << 16); }
__device__ __forceinline__ float bfhi(unsigned int u) { return __uint_as_float(u & 0xffff0000u); }

__global__ __launch_bounds__(256, 3)
void encoder_fused(const float* __restrict__ x,
                   const float* __restrict__ inw, const float* __restrict__ inb,
                   const float* __restrict__ ow,  const float* __restrict__ ob,
                   const float* __restrict__ w1,  const float* __restrict__ b1,
                   const float* __restrict__ w2,  const float* __restrict__ b2,
                   const float* __restrict__ w3,  const float* __restrict__ b3,
                   const float* __restrict__ g1,  const float* __restrict__ be1,
                   const float* __restrict__ g2,  const float* __restrict__ be2,
                   float* __restrict__ out)
{
    const int wv = threadIdx.x >> 6;          // wave id 0..3  (one n per wave)
    const int ln = threadIdx.x & 63;          // lane
    const int n  = blockIdx.x * NB + wv;

    __shared__ float4       sK[NB][3][LDIM];  // K fp32, chunk-major (broadcast b128 reads)
    __shared__ unsigned int sV[NB][LDIM][8];  // V bf16 packed (6 used, pad to 32B rows)

    // ---- load this lane's two x rows (l = ln, ln+64) ----
    float xr[2][EDIM];
    #pragma unroll
    for (int rr = 0; rr < 2; ++rr) {
        const float* xp = x + ((size_t)(ln + 64*rr) * NDIM + n) * EDIM;
        float4 a = *reinterpret_cast<const float4*>(xp);
        float4 b = *reinterpret_cast<const float4*>(xp + 4);
        float4 c = *reinterpret_cast<const float4*>(xp + 8);
        xr[rr][0]=a.x; xr[rr][1]=a.y; xr[rr][2]=a.z;  xr[rr][3]=a.w;
        xr[rr][4]=b.x; xr[rr][5]=b.y; xr[rr][6]=b.z;  xr[rr][7]=b.w;
        xr[rr][8]=c.x; xr[rr][9]=c.y; xr[rr][10]=c.z; xr[rr][11]=c.w;
    }

    const float SCALE = 0.2886751345948129f;   // 1/sqrt(12)
    const float L2E   = 1.4426950408889634f;

    // ---- QKV projection (weights via scalar loads) ----
    float qL[2][EDIM];    // q * SCALE * log2(e)
    float qq[2] = {0.f, 0.f};
    float knmx = 0.f;
    #pragma unroll
    for (int rr = 0; rr < 2; ++rr) {
        #pragma unroll
        for (int f = 0; f < EDIM; ++f) {
            float a = inb[f] + dot12g(inw + f * EDIM, xr[rr]);
            a *= SCALE;
            qq[rr] += a * a;
            qL[rr][f] = a * L2E;
        }
        float kv[EDIM];
        float kn = 0.f;
        #pragma unroll
        for (int f = 0; f < EDIM; ++f) {
            float a = inb[12 + f] + dot12g(inw + (12 + f) * EDIM, xr[rr]);
            kv[f] = a; kn += a * a;
        }
        knmx = fmaxf(knmx, kn);
        const int row = ln + 64 * rr;
        sK[wv][0][row] = make_float4(kv[0], kv[1], kv[2],  kv[3]);
        sK[wv][1][row] = make_float4(kv[4], kv[5], kv[6],  kv[7]);
        sK[wv][2][row] = make_float4(kv[8], kv[9], kv[10], kv[11]);
        #pragma unroll
        for (int f = 0; f < EDIM; ++f)
            kv[f] = inb[24 + f] + dot12g(inw + (24 + f) * EDIM, xr[rr]);
        unsigned int u0 = bfpair(kv[0],  kv[1]);
        unsigned int u1 = bfpair(kv[2],  kv[3]);
        unsigned int u2 = bfpair(kv[4],  kv[5]);
        unsigned int u3 = bfpair(kv[6],  kv[7]);
        unsigned int u4 = bfpair(kv[8],  kv[9]);
        unsigned int u5 = bfpair(kv[10], kv[11]);
        *reinterpret_cast<uint4*>(&sV[wv][row][0]) = make_uint4(u0, u1, u2, u3);
        *reinterpret_cast<uint2*>(&sV[wv][row][4]) = make_uint2(u4, u5);
    }

    // wave-local max ||k||^2 over this n's 128 rows
    float mk = knmx;
    #pragma unroll
    for (int off = 32; off > 0; off >>= 1) mk = fmaxf(mk, __shfl_xor(mk, off));
    // Cauchy-Schwarz bound (in log2 domain): s2 - M2 <= 0
    float M2[2];
    M2[0] = sqrtf(qq[0] * mk) * L2E;
    M2[1] = sqrtf(qq[1] * mk) * L2E;

    __syncthreads();

    // ---- single-pass attention ----
    float acc[2][EDIM];
    #pragma unroll
    for (int rr = 0; rr < 2; ++rr)
        #pragma unroll
        for (int e = 0; e < EDIM; ++e) acc[rr][e] = 0.f;
    float psum[2] = {0.f, 0.f};

    #pragma unroll 2
    for (int m = 0; m < LDIM; ++m) {
        float4 k0 = sK[wv][0][m], k1 = sK[wv][1][m], k2 = sK[wv][2][m];
        uint4 va = *reinterpret_cast<const uint4*>(&sV[wv][m][0]);
        uint2 vb = *reinterpret_cast<const uint2*>(&sV[wv][m][4]);
        float p[2];
        #pragma unroll
        for (int rr = 0; rr < 2; ++rr) {
            float s = qL[rr][0]*k0.x + qL[rr][1]*k0.y + qL[rr][2]*k0.z  + qL[rr][3]*k0.w
                    + qL[rr][4]*k1.x + qL[rr][5]*k1.y + qL[rr][6]*k1.z  + qL[rr][7]*k1.w
                    + qL[rr][8]*k2.x + qL[rr][9]*k2.y + qL[rr][10]*k2.z + qL[rr][11]*k2.w;
            p[rr] = ex2_(s - M2[rr]);
            psum[rr] += p[rr];
        }
        float v0 = bflo(va.x), v1 = bfhi(va.x), v2  = bflo(va.y), v3  = bfhi(va.y);
        float v4 = bflo(va.z), v5 = bfhi(va.z), v6  = bflo(va.w), v7  = bfhi(va.w);
        float v8 = bflo(vb.x), v9 = bfhi(vb.x), v10 = bflo(vb.y), v11 = bfhi(vb.y);
        #pragma unroll
        for (int rr = 0; rr < 2; ++rr) {
            acc[rr][0] += p[rr]*v0; acc[rr][1] += p[rr]*v1; acc[rr][2]  += p[rr]*v2;  acc[rr][3]  += p[rr]*v3;
            acc[rr][4] += p[rr]*v4; acc[rr][5] += p[rr]*v5; acc[rr][6]  += p[rr]*v6;  acc[rr][7]  += p[rr]*v7;
            acc[rr][8] += p[rr]*v8; acc[rr][9] += p[rr]*v9; acc[rr][10] += p[rr]*v10; acc[rr][11] += p[rr]*v11;
        }
    }

    float at[2][EDIM];
    #pragma unroll
    for (int rr = 0; rr < 2; ++rr) {
        float inv = rcp_(fmaxf(psum[rr], 1e-35f));
        #pragma unroll
        for (int e = 0; e < EDIM; ++e) at[rr][e] = acc[rr][e] * inv;
    }

    // ---- epilogue per row: out-proj + LN1 + MLP + LN2 + store ----
    #pragma unroll
    for (int rr = 0; rr < 2; ++rr) {
        float r[EDIM];
        #pragma unroll
        for (int f = 0; f < EDIM; ++f)
            r[f] = xr[rr][f] + ob[f] + dot12g(ow + f * EDIM, at[rr]);
        float mu = 0.f;
        #pragma unroll
        for (int e = 0; e < EDIM; ++e) mu += r[e];
        mu *= (1.0f / 12.0f);
        float var = 0.f;
        #pragma unroll
        for (int e = 0; e < EDIM; ++e) { float d = r[e] - mu; var += d * d; }
        var *= (1.0f / 12.0f);
        float rs = rsq_(var + 1e-5f);
        float y[EDIM];
        #pragma unroll
        for (int e = 0; e < EDIM; ++e)
            y[e] = (r[e] - mu) * rs * g1[e] + be1[e];

        float h1v[HDIM];
        #pragma unroll
        for (int h = 0; h < HDIM; ++h)
            h1v[h] = tanh_(b1[h] + dot12g(w1 + h * EDIM, y));
        float h2v[HDIM];
        #pragma unroll
        for (int g = 0; g < HDIM; ++g)
            h2v[g] = tanh_(b2[g] + dot32g(w2 + g * HDIM, h1v));
        float r2[EDIM];
        #pragma unroll
        for (int e = 0; e < EDIM; ++e)
            r2[e] = y[e] + tanh_(b3[e] + dot32g(w3 + e * HDIM, h2v));

        float mu2 = 0.f;
        #pragma unroll
        for (int e = 0; e < EDIM; ++e) mu2 += r2[e];
        mu2 *= (1.0f / 12.0f);
        float var2 = 0.f;
        #pragma unroll
        for (int e = 0; e < EDIM; ++e) { float d = r2[e] - mu2; var2 += d * d; }
        var2 *= (1.0f / 12.0f);
        float rs2 = rsq_(var2 + 1e-5f);
        float z[EDIM];
        #pragma unroll
        for (int e = 0; e < EDIM; ++e)
            z[e] = (r2[e] - mu2) * rs2 * g2[e] + be2[e];

        float* orow = out + ((size_t)(ln + 64*rr) * NDIM + n) * EDIM;
        *reinterpret_cast<float4*>(orow)     = make_float4(z[0], z[1], z[2],  z[3]);
        *reinterpret_cast<float4*>(orow + 4) = make_float4(z[4], z[5], z[6],  z[7]);
        *reinterpret_cast<float4*>(orow + 8) = make_float4(z[8], z[9], z[10], z[11]);
    }
}

extern "C" void kernel_launch(void* const* d_in, const int* in_sizes, int n_in,
                              void* d_out, int out_size, void* d_ws, size_t ws_size,
                              hipStream_t stream) {
    const float* x   = (const float*)d_in[0];
    const float* inw = (const float*)d_in[1];
    const float* inb = (const float*)d_in[2];
    const float* ow  = (const float*)d_in[3];
    const float* ob  = (const float*)d_in[4];
    const float* w1  = (const float*)d_in[5];
    const float* b1  = (const float*)d_in[6];
    const float* w2  = (const float*)d_in[7];
    const float* b2  = (const float*)d_in[8];
    const float* w3  = (const float*)d_in[9];
    const float* b3  = (const float*)d_in[10];
    const float* g1  = (const float*)d_in[11];
    const float* be1 = (const float*)d_in[12];
    const float* g2  = (const float*)d_in[13];
    const float* be2 = (const float*)d_in[14];
    float* out = (float*)d_out;

    encoder_fused<<<dim3(NDIM / NB), dim3(64 * NB), 0, stream>>>(
        x, inw, inb, ow, ob, w1, b1, w2, b2, w3, b3, g1, be1, g2, be2, out);
}

// Round 3
// 92.822 us; speedup vs baseline: 3.7208x; 2.9962x over previous
//
#include <hip/hip_runtime.h>

#define NDIM 4096
#define LDIM 128
#define EDIM 12
#define HDIM 32

typedef float f2 __attribute__((ext_vector_type(2)));

#ifndef __has_builtin
#define __has_builtin(x) 0
#endif

__device__ __forceinline__ float ex2_(float v) {
#if __has_builtin(__builtin_amdgcn_exp2f)
    return __builtin_amdgcn_exp2f(v);
#else
    return exp2f(v);
#endif
}
__device__ __forceinline__ float rcp_(float v) {
#if __has_builtin(__builtin_amdgcn_rcpf)
    return __builtin_amdgcn_rcpf(v);
#else
    return 1.0f / v;
#endif
}
__device__ __forceinline__ float rsq_(float v) {
#if __has_builtin(__builtin_amdgcn_rsqf)
    return __builtin_amdgcn_rsqf(v);
#else
    return rsqrtf(v);
#endif
}
// tanh(v) = 1 - 2/(e^{2v}+1)
__device__ __forceinline__ float tanh_(float v) {
    float t = ex2_(v * 2.8853900817779268f);
    return 1.0f - 2.0f * rcp_(t + 1.0f);
}

__device__ __forceinline__ f2 lo2(float4 v) { f2 r; r.x = v.x; r.y = v.y; return r; }
__device__ __forceinline__ f2 hi2(float4 v) { f2 r; r.x = v.z; r.y = v.w; return r; }
__device__ __forceinline__ f2 pf(f2 a, f2 b, f2 c) { return __builtin_elementwise_fma(a, b, c); }

// dot(12-elem weight row (global, uniform -> s_load), f2[6]) via packed fma
__device__ __forceinline__ float dot12p(const float* __restrict__ w, const f2* v) {
    const float4* w4 = reinterpret_cast<const float4*>(w);
    float4 a = w4[0], b = w4[1], c = w4[2];
    f2 s = v[0] * lo2(a);
    s = pf(v[1], hi2(a), s);
    s = pf(v[2], lo2(b), s);
    s = pf(v[3], hi2(b), s);
    s = pf(v[4], lo2(c), s);
    s = pf(v[5], hi2(c), s);
    return s.x + s.y;
}
__device__ __forceinline__ float dot32p(const float* __restrict__ w, const f2* v) {
    const float4* w4 = reinterpret_cast<const float4*>(w);
    f2 s = {0.f, 0.f};
    #pragma unroll
    for (int c = 0; c < 8; ++c) {
        float4 t = w4[c];
        s = pf(v[2*c],   lo2(t), s);
        s = pf(v[2*c+1], hi2(t), s);
    }
    return s.x + s.y;
}

__global__ __launch_bounds__(256, 4)
void encoder_fused(const float* __restrict__ x,
                   const float* __restrict__ inw, const float* __restrict__ inb,
                   const float* __restrict__ ow,  const float* __restrict__ ob,
                   const float* __restrict__ w1,  const float* __restrict__ b1,
                   const float* __restrict__ w2,  const float* __restrict__ b2,
                   const float* __restrict__ w3,  const float* __restrict__ b3,
                   const float* __restrict__ g1,  const float* __restrict__ be1,
                   const float* __restrict__ g2,  const float* __restrict__ be2,
                   float* __restrict__ out)
{
    const int tid = threadIdx.x;
    const int p   = tid >> 7;         // n within block (0..1)
    const int l   = tid & 127;        // sequence row (one per thread)
    const int wv2 = (tid >> 6) & 1;   // wave within n-pair
    const int ln  = tid & 63;
    const int n   = blockIdx.x * 2 + p;

    __shared__ float4 sK[2][3][LDIM];   // K fp32 chunk-major (broadcast b128 reads)
    __shared__ float4 sV[2][3][LDIM];   // V fp32 chunk-major
    __shared__ float  sMk[2][2];

    // ---- load this thread's x row ----
    const float* xp = x + ((size_t)l * NDIM + n) * EDIM;
    float4 xa = *reinterpret_cast<const float4*>(xp);
    float4 xb = *reinterpret_cast<const float4*>(xp + 4);
    float4 xc = *reinterpret_cast<const float4*>(xp + 8);
    f2 xr[6] = {lo2(xa), hi2(xa), lo2(xb), hi2(xb), lo2(xc), hi2(xc)};

    const float SCALE = 0.2886751345948129f;   // 1/sqrt(12)
    const float L2E   = 1.4426950408889634f;

    // ---- QKV projection (weights via scalar loads) ----
    f2 qL[6];                 // q * SCALE * log2(e), packed
    float qq = 0.f;
    #pragma unroll
    for (int f = 0; f < EDIM; f += 2) {
        float a0 = inb[f]     + dot12p(inw + f * EDIM,       xr);
        float a1 = inb[f + 1] + dot12p(inw + (f + 1) * EDIM, xr);
        a0 *= SCALE; a1 *= SCALE;
        qq += a0 * a0 + a1 * a1;
        f2 t; t.x = a0 * L2E; t.y = a1 * L2E;
        qL[f >> 1] = t;
    }
    float kv[EDIM];
    float kn = 0.f;
    #pragma unroll
    for (int f = 0; f < EDIM; ++f) {
        float a = inb[12 + f] + dot12p(inw + (12 + f) * EDIM, xr);
        kv[f] = a; kn += a * a;
    }
    sK[p][0][l] = make_float4(kv[0], kv[1], kv[2],  kv[3]);
    sK[p][1][l] = make_float4(kv[4], kv[5], kv[6],  kv[7]);
    sK[p][2][l] = make_float4(kv[8], kv[9], kv[10], kv[11]);
    #pragma unroll
    for (int f = 0; f < EDIM; ++f)
        kv[f] = inb[24 + f] + dot12p(inw + (24 + f) * EDIM, xr);
    sV[p][0][l] = make_float4(kv[0], kv[1], kv[2],  kv[3]);
    sV[p][1][l] = make_float4(kv[4], kv[5], kv[6],  kv[7]);
    sV[p][2][l] = make_float4(kv[8], kv[9], kv[10], kv[11]);

    // wave-level max ||k||^2, then across the n's two waves via LDS
    float mk = kn;
    #pragma unroll
    for (int off = 32; off > 0; off >>= 1) mk = fmaxf(mk, __shfl_xor(mk, off));
    if (ln == 0) sMk[p][wv2] = mk;
    __syncthreads();
    // Cauchy-Schwarz bound in log2 domain: s*L2E - M2 <= 0
    const float M2 = sqrtf(qq * fmaxf(sMk[p][0], sMk[p][1])) * L2E;

    // ---- single-pass attention (packed f32 math) ----
    f2 acc[6];
    #pragma unroll
    for (int j = 0; j < 6; ++j) { acc[j].x = 0.f; acc[j].y = 0.f; }
    float psum = 0.f;

    #pragma unroll 2
    for (int m = 0; m < LDIM; ++m) {
        float4 k0 = sK[p][0][m], k1 = sK[p][1][m], k2 = sK[p][2][m];
        f2 s2 = qL[0] * lo2(k0);
        s2 = pf(qL[1], hi2(k0), s2);
        s2 = pf(qL[2], lo2(k1), s2);
        s2 = pf(qL[3], hi2(k1), s2);
        s2 = pf(qL[4], lo2(k2), s2);
        s2 = pf(qL[5], hi2(k2), s2);
        float pe = ex2_(s2.x + s2.y - M2);
        psum += pe;
        float4 v0 = sV[p][0][m], v1 = sV[p][1][m], v2 = sV[p][2][m];
        f2 pp; pp.x = pe; pp.y = pe;
        acc[0] = pf(pp, lo2(v0), acc[0]);
        acc[1] = pf(pp, hi2(v0), acc[1]);
        acc[2] = pf(pp, lo2(v1), acc[2]);
        acc[3] = pf(pp, hi2(v1), acc[3]);
        acc[4] = pf(pp, lo2(v2), acc[4]);
        acc[5] = pf(pp, hi2(v2), acc[5]);
    }
    const float inv = rcp_(fmaxf(psum, 1e-35f));
    f2 at[6];
    #pragma unroll
    for (int j = 0; j < 6; ++j) { at[j].x = acc[j].x * inv; at[j].y = acc[j].y * inv; }

    // ---- out projection + residual + LN1 ----
    f2 r[6];
    #pragma unroll
    for (int f = 0; f < EDIM; f += 2) {
        float a0 = ob[f]     + dot12p(ow + f * EDIM,       at);
        float a1 = ob[f + 1] + dot12p(ow + (f + 1) * EDIM, at);
        f2 t; t.x = a0; t.y = a1;
        r[f >> 1] = xr[f >> 1] + t;
    }
    f2 sm = r[0] + r[1] + r[2] + r[3] + r[4] + r[5];
    float mu = (sm.x + sm.y) * (1.0f / 12.0f);
    f2 mub; mub.x = mu; mub.y = mu;
    f2 vs = {0.f, 0.f};
    #pragma unroll
    for (int j = 0; j < 6; ++j) { f2 d = r[j] - mub; vs = pf(d, d, vs); }
    float rs = rsq_((vs.x + vs.y) * (1.0f / 12.0f) + 1e-5f);
    f2 rsb; rsb.x = rs; rsb.y = rs;
    const f2* g1p  = reinterpret_cast<const f2*>(g1);
    const f2* be1p = reinterpret_cast<const f2*>(be1);
    f2 y[6];
    #pragma unroll
    for (int j = 0; j < 6; ++j)
        y[j] = pf((r[j] - mub) * rsb, g1p[j], be1p[j]);

    // ---- MLP: 12 -> 32 -> 32 -> 12, tanh each (packed dots) ----
    f2 h1[16];
    #pragma unroll
    for (int h = 0; h < HDIM; h += 2) {
        float a0 = tanh_(b1[h]     + dot12p(w1 + h * EDIM,       y));
        float a1 = tanh_(b1[h + 1] + dot12p(w1 + (h + 1) * EDIM, y));
        f2 t; t.x = a0; t.y = a1;
        h1[h >> 1] = t;
    }
    f2 h2[16];
    #pragma unroll
    for (int g = 0; g < HDIM; g += 2) {
        float a0 = tanh_(b2[g]     + dot32p(w2 + g * HDIM,       h1));
        float a1 = tanh_(b2[g + 1] + dot32p(w2 + (g + 1) * HDIM, h1));
        f2 t; t.x = a0; t.y = a1;
        h2[g >> 1] = t;
    }
    f2 r2[6];
    #pragma unroll
    for (int e = 0; e < EDIM; e += 2) {
        float a0 = tanh_(b3[e]     + dot32p(w3 + e * HDIM,       h2));
        float a1 = tanh_(b3[e + 1] + dot32p(w3 + (e + 1) * HDIM, h2));
        f2 t; t.x = a0; t.y = a1;
        r2[e >> 1] = y[e >> 1] + t;
    }

    // ---- LN2 + store ----
    f2 sm2 = r2[0] + r2[1] + r2[2] + r2[3] + r2[4] + r2[5];
    float mu2 = (sm2.x + sm2.y) * (1.0f / 12.0f);
    f2 mub2; mub2.x = mu2; mub2.y = mu2;
    f2 vs2 = {0.f, 0.f};
    #pragma unroll
    for (int j = 0; j < 6; ++j) { f2 d = r2[j] - mub2; vs2 = pf(d, d, vs2); }
    float rs2 = rsq_((vs2.x + vs2.y) * (1.0f / 12.0f) + 1e-5f);
    f2 rsb2; rsb2.x = rs2; rsb2.y = rs2;
    const f2* g2p  = reinterpret_cast<const f2*>(g2);
    const f2* be2p = reinterpret_cast<const f2*>(be2);
    f2 z[6];
    #pragma unroll
    for (int j = 0; j < 6; ++j)
        z[j] = pf((r2[j] - mub2) * rsb2, g2p[j], be2p[j]);

    float* orow = out + ((size_t)l * NDIM + n) * EDIM;
    *reinterpret_cast<float4*>(orow)     = make_float4(z[0].x, z[0].y, z[1].x, z[1].y);
    *reinterpret_cast<float4*>(orow + 4) = make_float4(z[2].x, z[2].y, z[3].x, z[3].y);
    *reinterpret_cast<float4*>(orow + 8) = make_float4(z[4].x, z[4].y, z[5].x, z[5].y);
}

extern "C" void kernel_launch(void* const* d_in, const int* in_sizes, int n_in,
                              void* d_out, int out_size, void* d_ws, size_t ws_size,
                              hipStream_t stream) {
    const float* x   = (const float*)d_in[0];
    const float* inw = (const float*)d_in[1];
    const float* inb = (const float*)d_in[2];
    const float* ow  = (const float*)d_in[3];
    const float* ob  = (const float*)d_in[4];
    const float* w1  = (const float*)d_in[5];
    const float* b1  = (const float*)d_in[6];
    const float* w2  = (const float*)d_in[7];
    const float* b2  = (const float*)d_in[8];
    const float* w3  = (const float*)d_in[9];
    const float* b3  = (const float*)d_in[10];
    const float* g1  = (const float*)d_in[11];
    const float* be1 = (const float*)d_in[12];
    const float* g2  = (const float*)d_in[13];
    const float* be2 = (const float*)d_in[14];
    float* out = (float*)d_out;

    encoder_fused<<<dim3(NDIM / 2), dim3(256), 0, stream>>>(
        x, inw, inb, ow, ob, w1, b1, w2, b2, w3, b3, g1, be1, g2, be2, out);
}